// Round 12
// baseline (2517.430 us; speedup 1.0000x reference)
//
#include <hip/hip_runtime.h>
#include <math.h>

#define NN_ 20000
#define EE_ 320000
#define SHP 68      // padded row stride (floats) for [128][SHP] activation tile
#define EPH 80000   // edges per phase (E = 4 * EPH exactly)

__device__ __forceinline__ float silu_f(float x) { return x / (1.0f + expf(-x)); }

// ---- GEMM-tiled dense layer over a 128-edge LDS tile (in-place, silu) ---------
template<int KD>
__device__ __forceinline__ void layer_step(float* __restrict__ sh_h,
                                           const float* __restrict__ sh_w,
                                           int wavebase, int eg, int jg) {
  const int jb = jg * 8;
  float acc[8][8];
#pragma unroll
  for (int ee = 0; ee < 8; ++ee)
#pragma unroll
    for (int jj = 0; jj < 8; ++jj) acc[ee][jj] = 0.f;

#pragma unroll
  for (int kc = 0; kc < KD; kc += 4) {
    float4 w4[4][2];
#pragma unroll
    for (int kk = 0; kk < 4; ++kk) {
      w4[kk][0] = *(const float4*)&sh_w[(kc + kk) * 64 + jb];
      w4[kk][1] = *(const float4*)&sh_w[(kc + kk) * 64 + jb + 4];
    }
    float4 h4[8];
#pragma unroll
    for (int ee = 0; ee < 8; ++ee)
      h4[ee] = *(const float4*)&sh_h[(wavebase + eg + 8 * ee) * SHP + kc];
#pragma unroll
    for (int kk = 0; kk < 4; ++kk) {
#pragma unroll
      for (int ee = 0; ee < 8; ++ee) {
        const float hv = ((const float*)&h4[ee])[kk];
        acc[ee][0] = fmaf(hv, w4[kk][0].x, acc[ee][0]);
        acc[ee][1] = fmaf(hv, w4[kk][0].y, acc[ee][1]);
        acc[ee][2] = fmaf(hv, w4[kk][0].z, acc[ee][2]);
        acc[ee][3] = fmaf(hv, w4[kk][0].w, acc[ee][3]);
        acc[ee][4] = fmaf(hv, w4[kk][1].x, acc[ee][4]);
        acc[ee][5] = fmaf(hv, w4[kk][1].y, acc[ee][5]);
        acc[ee][6] = fmaf(hv, w4[kk][1].z, acc[ee][6]);
        acc[ee][7] = fmaf(hv, w4[kk][1].w, acc[ee][7]);
      }
    }
  }
#pragma unroll
  for (int ee = 0; ee < 8; ++ee) {
    float* dst = &sh_h[(wavebase + eg + 8 * ee) * SHP + jb];
    float4 lo = {silu_f(acc[ee][0]), silu_f(acc[ee][1]), silu_f(acc[ee][2]), silu_f(acc[ee][3])};
    float4 hi = {silu_f(acc[ee][4]), silu_f(acc[ee][5]), silu_f(acc[ee][6]), silu_f(acc[ee][7])};
    *(float4*)dst = lo;
    *(float4*)(dst + 4) = hi;
  }
}

// ---- same blocking, no activation, output -> global r2 rows -------------------
__device__ __forceinline__ void gemm_chunk_out(const float* __restrict__ sh_h,
                                               const float* __restrict__ sh_w,
                                               int wavebase, int eg, int jg,
                                               float* __restrict__ dst_base) {
  const int jb = jg * 8;
  float acc[8][8];
#pragma unroll
  for (int ee = 0; ee < 8; ++ee)
#pragma unroll
    for (int jj = 0; jj < 8; ++jj) acc[ee][jj] = 0.f;

#pragma unroll
  for (int kc = 0; kc < 64; kc += 4) {
    float4 w4[4][2];
#pragma unroll
    for (int kk = 0; kk < 4; ++kk) {
      w4[kk][0] = *(const float4*)&sh_w[(kc + kk) * 64 + jb];
      w4[kk][1] = *(const float4*)&sh_w[(kc + kk) * 64 + jb + 4];
    }
    float4 h4[8];
#pragma unroll
    for (int ee = 0; ee < 8; ++ee)
      h4[ee] = *(const float4*)&sh_h[(wavebase + eg + 8 * ee) * SHP + kc];
#pragma unroll
    for (int kk = 0; kk < 4; ++kk) {
#pragma unroll
      for (int ee = 0; ee < 8; ++ee) {
        const float hv = ((const float*)&h4[ee])[kk];
        acc[ee][0] = fmaf(hv, w4[kk][0].x, acc[ee][0]);
        acc[ee][1] = fmaf(hv, w4[kk][0].y, acc[ee][1]);
        acc[ee][2] = fmaf(hv, w4[kk][0].z, acc[ee][2]);
        acc[ee][3] = fmaf(hv, w4[kk][0].w, acc[ee][3]);
        acc[ee][4] = fmaf(hv, w4[kk][1].x, acc[ee][4]);
        acc[ee][5] = fmaf(hv, w4[kk][1].y, acc[ee][5]);
        acc[ee][6] = fmaf(hv, w4[kk][1].z, acc[ee][6]);
        acc[ee][7] = fmaf(hv, w4[kk][1].w, acc[ee][7]);
      }
    }
  }
#pragma unroll
  for (int ee = 0; ee < 8; ++ee) {
    float* dst = dst_base + (size_t)(wavebase + eg + 8 * ee) * 256 + jb;
    float4 lo = {acc[ee][0], acc[ee][1], acc[ee][2], acc[ee][3]};
    float4 hi = {acc[ee][4], acc[ee][5], acc[ee][6], acc[ee][7]};
    *(float4*)dst = lo;
    *(float4*)(dst + 4) = hi;
  }
}

__device__ __forceinline__ void load_w(const float* __restrict__ W, int nfloat,
                                       float* __restrict__ dst, int t) {
  for (int i = t * 4; i < nfloat; i += 512) *(float4*)(dst + i) = *(const float4*)(W + i);
}

// ================= CSR construction (receiver-sorted edge ids) ====================
__global__ __launch_bounds__(256) void k_hist(const int* __restrict__ receivers,
                                              int* __restrict__ hist) {
  const int e = blockIdx.x * 256 + threadIdx.x;
  atomicAdd(&hist[receivers[e]], 1);
}

__global__ __launch_bounds__(1024) void k_scan(const int* __restrict__ hist,
                                               int* __restrict__ offs,
                                               int* __restrict__ cursor) {
  __shared__ int lds[1024];
  __shared__ int carry_s;
  const int t = threadIdx.x;
  if (t == 0) carry_s = 0;
  __syncthreads();
  for (int base = 0; base < NN_; base += 1024) {
    const int i = base + t;
    const int v = (i < NN_) ? hist[i] : 0;
    lds[t] = v;
    __syncthreads();
    for (int d = 1; d < 1024; d <<= 1) {
      const int tv = (t >= d) ? lds[t - d] : 0;
      __syncthreads();
      lds[t] += tv;
      __syncthreads();
    }
    const int inc = lds[t];
    const int c = carry_s;
    if (i < NN_) {
      const int off = c + inc - v;
      offs[i] = off;
      cursor[i] = off;
    }
    __syncthreads();
    if (t == 0) carry_s = c + lds[1023];
    __syncthreads();
  }
  if (t == 0) offs[NN_] = carry_s;
}

__global__ __launch_bounds__(256) void k_scatter(const int* __restrict__ receivers,
                                                 int* __restrict__ cursor,
                                                 int* __restrict__ edge_id) {
  const int e = blockIdx.x * 256 + threadIdx.x;
  const int r = receivers[e];
  const int pos = atomicAdd(&cursor[r], 1);
  edge_id[pos] = e;
}

// ---------------- K1a: per-edge layer-1 (geometry + tiled radial MLP + msg) -------
__global__ __launch_bounds__(128) void k1a_radial(
    const float* __restrict__ disp, const int* __restrict__ species,
    const int* __restrict__ senders,
    const float* __restrict__ lin1,
    const float* __restrict__ rw0, const float* __restrict__ rw1,
    const float* __restrict__ rw2, const float* __restrict__ rw3,
    float* __restrict__ buf1, float* __restrict__ rbc_g, float* __restrict__ y1_g) {
  __shared__ float sh_h[128 * SHP];
  __shared__ float sh_w[64 * 64];
  const int t = threadIdx.x;
  const int e0 = blockIdx.x * 128;
  const int e = e0 + t;

  const float dx = disp[e * 3 + 0], dy = disp[e * 3 + 1], dz = disp[e * 3 + 2];
  const float sq = dx * dx + dy * dy + dz * dz;
  const float rn = sqrtf(sq);
  const float inv = (rn == 0.f) ? 1.f : (1.f / rn);
  const float u = rn * 0.2f;
  float fc;
  {
    const float u2 = u * u;
    fc = 1.f - 6.f * u2 + 8.f * u2 * u - 3.f * u2 * u2;
    fc = (u < 1.f) ? fc : 0.f;
  }
  float rb[8];
#pragma unroll
  for (int k = 0; k < 8; ++k) {
    const float wk = (float)(k + 1) * 3.14159265358979323846f;
    const float s = (rn == 0.f) ? (wk * 0.2f) : (sinf(wk * u) * inv);
    rb[k] = 0.4f * s * fc;
  }
  float4 r0 = {rb[0], rb[1], rb[2], rb[3]};
  float4 r1 = {rb[4], rb[5], rb[6], rb[7]};
  *(float4*)(rbc_g + e * 8) = r0;
  *(float4*)(rbc_g + e * 8 + 4) = r1;
  const float y1x = 1.7320508075688772f * dx * inv;
  const float y1y = 1.7320508075688772f * dy * inv;
  const float y1z = 1.7320508075688772f * dz * inv;
  float4 y4 = {y1x, y1y, y1z, 0.f};
  *(float4*)(y1_g + e * 4) = y4;
  *(float4*)&sh_h[t * SHP] = r0;
  *(float4*)&sh_h[t * SHP + 4] = r1;

  const int wavebase = (t >> 6) * 64;
  const int lane = t & 63;
  const int eg = lane >> 3, jg = lane & 7;

  load_w(rw0, 8 * 64, sh_w, t);
  __syncthreads();
  layer_step<8>(sh_h, sh_w, wavebase, eg, jg);
  __syncthreads();
  load_w(rw1, 64 * 64, sh_w, t);
  __syncthreads();
  layer_step<64>(sh_h, sh_w, wavebase, eg, jg);
  __syncthreads();
  load_w(rw2, 64 * 64, sh_w, t);
  __syncthreads();
  layer_step<64>(sh_h, sh_w, wavebase, eg, jg);
  __syncthreads();

  // ---- head 64->16 (thread t <-> edge t; rw3 via scalar loads) ----
  float R[16];
#pragma unroll
  for (int c = 0; c < 16; ++c) R[c] = 0.f;
  for (int k = 0; k < 64; ++k) {
    const float h = sh_h[t * SHP + k];
#pragma unroll
    for (int c = 0; c < 16; ++c) R[c] = fmaf(h, rw3[k * 16 + c], R[c]);
  }

  const int sp = species[senders[e]];
  float m[32];
#pragma unroll
  for (int c = 0; c < 8; ++c) {
    const float sc = lin1[sp * 8 + c];
    m[c] = sc * R[c];
    const float mv = sc * R[8 + c];
    m[8 + c * 3 + 0] = mv * y1x;
    m[8 + c * 3 + 1] = mv * y1y;
    m[8 + c * 3 + 2] = mv * y1z;
  }
  float* dst = buf1 + (size_t)e * 32;
#pragma unroll
  for (int q = 0; q < 8; ++q) {
    float4 v = {m[q * 4 + 0], m[q * 4 + 1], m[q * 4 + 2], m[q * 4 + 3]};
    *(float4*)(dst + q * 4) = v;
  }
}

// ---------------- K3a: layer-2 radial MLP + 64->256 head GEMM (CSR order) ---------
// Processes 128 CSR positions per block; writes R2 rows to r2buf[p - pbase].
__global__ __launch_bounds__(128) void k3a_fused(
    const float* __restrict__ rbc_g, const int* __restrict__ edge_id,
    const float* __restrict__ rw0, const float* __restrict__ rw1,
    const float* __restrict__ rw2, const float* __restrict__ rw3,
    float* __restrict__ r2buf, int pbase) {
  __shared__ float sh_h[128 * SHP];
  __shared__ float sh_w[64 * 64];
  const int t = threadIdx.x;
  const int p = pbase + blockIdx.x * 128 + t;
  const int eid = edge_id[p];

  *(float4*)&sh_h[t * SHP] = *(const float4*)(rbc_g + (size_t)eid * 8);
  *(float4*)&sh_h[t * SHP + 4] = *(const float4*)(rbc_g + (size_t)eid * 8 + 4);

  const int wavebase = (t >> 6) * 64;
  const int lane = t & 63;
  const int eg = lane >> 3, jg = lane & 7;

  load_w(rw0, 8 * 64, sh_w, t);
  __syncthreads();
  layer_step<8>(sh_h, sh_w, wavebase, eg, jg);
  __syncthreads();
  load_w(rw1, 64 * 64, sh_w, t);
  __syncthreads();
  layer_step<64>(sh_h, sh_w, wavebase, eg, jg);
  __syncthreads();
  load_w(rw2, 64 * 64, sh_w, t);
  __syncthreads();
  layer_step<64>(sh_h, sh_w, wavebase, eg, jg);

  // ---- R2 = h2(128x64) @ rw3(64x256), 4 column-chunks of 64 ----
  float* block_base = r2buf + (size_t)(blockIdx.x * 128) * 256;
  for (int c = 0; c < 4; ++c) {
    __syncthreads();  // prev chunk's sh_w reads (or layer3 sh_h writes) done
    // stage rw3[:, c*64 .. c*64+64) -> sh_w[k][j]
    for (int i = t * 4; i < 4096; i += 512) {
      const int row = i >> 6, col = i & 63;
      *(float4*)&sh_w[i] = *(const float4*)&rw3[row * 256 + c * 64 + col];
    }
    __syncthreads();
    gemm_chunk_out(sh_h, sh_w, wavebase, eg, jg, block_base + c * 64);
  }
}

// ---------------- K3b: thin gather — agg2[n][ch] += sum tp * R2 -------------------
__global__ __launch_bounds__(256) void k3b_phase(
    const float* __restrict__ r2buf, const float* __restrict__ y1_g,
    const int* __restrict__ senders,
    const int* __restrict__ offs, const int* __restrict__ edge_id,
    const float* __restrict__ s2_g, const float* __restrict__ v2_g,
    float* __restrict__ agg2, int pbase, int pend) {
  const int n = blockIdx.x;
  const int ch = threadIdx.x;
  const int beg = offs[n], end = offs[n + 1];
  const int lo = beg > pbase ? beg : pbase;
  const int hi = end < pend ? end : pend;
  if (lo >= hi) return;
  const bool is_s = ch < 128;
  const int c3 = (ch - 128) * 3;
  float acc = 0.f;
  for (int i = lo; i < hi; ++i) {
    const int eid = __builtin_amdgcn_readfirstlane(edge_id[i]);
    const int s = __builtin_amdgcn_readfirstlane(senders[eid]);
    const float rv = r2buf[(size_t)(i - pbase) * 256 + ch];  // streaming, coalesced
    float tp;
    if (is_s) {
      tp = s2_g[(size_t)s * 128 + ch];
    } else {
      const float y1x = y1_g[eid * 4 + 0];
      const float y1y = y1_g[eid * 4 + 1];
      const float y1z = y1_g[eid * 4 + 2];
      tp = (v2_g[(size_t)s * 384 + c3 + 0] * y1x +
            v2_g[(size_t)s * 384 + c3 + 1] * y1y +
            v2_g[(size_t)s * 384 + c3 + 2] * y1z) * 0.5773502691896258f;
    }
    acc = fmaf(tp, rv, acc);
  }
  agg2[(size_t)n * 256 + ch] += acc;  // phases serialized on stream; agg2 pre-zeroed
}

// ---------------- K1b: per-node gather of layer-1 messages ------------------------
__global__ __launch_bounds__(256) void k1b_gather(
    const float* __restrict__ buf1, const int* __restrict__ offs,
    const int* __restrict__ edge_id,
    float* __restrict__ agg_s, float* __restrict__ agg_v) {
  const int n = blockIdx.x * 8 + (threadIdx.x >> 5);
  const int ch = threadIdx.x & 31;
  const int beg = offs[n], end = offs[n + 1];
  float acc = 0.f;
  for (int i = beg; i < end; ++i) {
    const int eid = edge_id[i];
    acc += buf1[(size_t)eid * 32 + ch];
  }
  if (ch < 8) agg_s[n * 8 + ch] = acc;
  else agg_v[n * 24 + (ch - 8)] = acc;
}

// ---------------- K2a: per-node layer-1 update (scal, x0, x1) ---------------------
__global__ __launch_bounds__(64) void k2a_node(
    const float* __restrict__ agg_s, const float* __restrict__ agg_v,
    const int* __restrict__ species,
    const float* __restrict__ w2s, const float* __restrict__ w2v,
    const float* __restrict__ skip1,
    float* __restrict__ x0_g, float* __restrict__ x1_g) {
  const int n = blockIdx.x;
  const int l = threadIdx.x;
  __shared__ float g_lds[128];
  const int sp = species[n];
  float as[8];
#pragma unroll
  for (int k = 0; k < 8; ++k) as[k] = agg_s[n * 8 + k] * 0.25f;
  float sc[4];
#pragma unroll
  for (int j = 0; j < 4; ++j) {
    const int d = l * 4 + j;
    float a = skip1[(sp * 9) * 256 + d];
#pragma unroll
    for (int k = 0; k < 8; ++k) a = fmaf(as[k], w2s[k * 256 + d], a);
    sc[j] = silu_f(a);
  }
  if (l < 32) {
#pragma unroll
    for (int j = 0; j < 4; ++j) x0_g[n * 128 + l * 4 + j] = sc[j];
  } else {
#pragma unroll
    for (int j = 0; j < 4; ++j) g_lds[(l - 32) * 4 + j] = sc[j];
  }
  __syncthreads();
  float av[24];
#pragma unroll
  for (int k = 0; k < 24; ++k) av[k] = agg_v[n * 24 + k] * 0.25f;
#pragma unroll
  for (int h = 0; h < 2; ++h) {
    const int d = l + h * 64;
    const float g = g_lds[d];
    float v0 = 0.f, v1 = 0.f, v2v = 0.f;
#pragma unroll
    for (int c = 0; c < 8; ++c) {
      const float w = w2v[c * 128 + d];
      v0 = fmaf(av[c * 3 + 0], w, v0);
      v1 = fmaf(av[c * 3 + 1], w, v1);
      v2v = fmaf(av[c * 3 + 2], w, v2v);
    }
    x1_g[(n * 3 + 0) * 128 + d] = v0 * g;
    x1_g[(n * 3 + 1) * 128 + d] = v1 * g;
    x1_g[(n * 3 + 2) * 128 + d] = v2v * g;
  }
}

// ---------------- K2b: node GEMMs (s2, v2, species-skip) --------------------------
__global__ __launch_bounds__(256) void k2b_gemm(
    const float* __restrict__ x0_g, const float* __restrict__ x1_g,
    const int* __restrict__ species,
    const float* __restrict__ lin1s, const float* __restrict__ lin1v,
    const float* __restrict__ skip2,
    float* __restrict__ s2_g, float* __restrict__ v2_g,
    float* __restrict__ skipv_g) {
  const int w = __builtin_amdgcn_readfirstlane((int)(threadIdx.x >> 6));
  const int l = threadIdx.x & 63;
  const int nbase = blockIdx.x * 32 + w * 8;
  float s2a[8] = {}, s2b[8] = {}, ska[8] = {}, skb[8] = {};
  float v2a[8][3] = {}, v2b[8][3] = {};
  int sp[8];
#pragma unroll
  for (int nn = 0; nn < 8; ++nn) sp[nn] = species[nbase + nn];
  for (int c = 0; c < 128; ++c) {
    const float wA0 = lin1s[c * 128 + l];
    const float wA1 = lin1s[c * 128 + 64 + l];
    const float wB0 = lin1v[c * 128 + l];
    const float wB1 = lin1v[c * 128 + 64 + l];
#pragma unroll
    for (int nn = 0; nn < 8; ++nn) {
      const int n = nbase + nn;
      const float x0v = x0_g[n * 128 + c];
      const float wS0 = skip2[sp[nn] * 16384 + c * 128 + l];
      const float wS1 = skip2[sp[nn] * 16384 + c * 128 + 64 + l];
      s2a[nn] = fmaf(x0v, wA0, s2a[nn]);
      s2b[nn] = fmaf(x0v, wA1, s2b[nn]);
      ska[nn] = fmaf(x0v, wS0, ska[nn]);
      skb[nn] = fmaf(x0v, wS1, skb[nn]);
#pragma unroll
      for (int i = 0; i < 3; ++i) {
        const float x1v = x1_g[(n * 3 + i) * 128 + c];
        v2a[nn][i] = fmaf(x1v, wB0, v2a[nn][i]);
        v2b[nn][i] = fmaf(x1v, wB1, v2b[nn][i]);
      }
    }
  }
#pragma unroll
  for (int nn = 0; nn < 8; ++nn) {
    const int n = nbase + nn;
    s2_g[n * 128 + l] = s2a[nn];
    s2_g[n * 128 + 64 + l] = s2b[nn];
    skipv_g[n * 128 + l] = ska[nn];
    skipv_g[n * 128 + 64 + l] = skb[nn];
#pragma unroll
    for (int i = 0; i < 3; ++i) {
      v2_g[n * 384 + l * 3 + i] = v2a[nn][i];
      v2_g[n * 384 + (64 + l) * 3 + i] = v2b[nn][i];
    }
  }
}

// ---------------- K4: final node update + readout ---------------------------------
__global__ __launch_bounds__(256) void k4_node(
    const float* __restrict__ agg2, const float* __restrict__ skipv,
    const float* __restrict__ w2, const float* __restrict__ readout,
    float* __restrict__ out) {
  __shared__ float tile[64 * 65];
  __shared__ float partial[256];
  const int t = threadIdx.x;
  const int w = __builtin_amdgcn_readfirstlane((int)(threadIdx.x >> 6));
  const int l = t & 63;
  const int n0 = blockIdx.x * 64;
  const int n = n0 + l;
  float acc[32];
#pragma unroll
  for (int j = 0; j < 32; ++j) acc[j] = 0.f;
  for (int ko = 0; ko < 256; ko += 64) {
    __syncthreads();
#pragma unroll
    for (int rep = 0; rep < 16; ++rep) {
      const int lin = rep * 256 + t;
      const int node = lin >> 6, kk = lin & 63;
      const int gn = n0 + node;
      tile[kk * 65 + node] = (gn < NN_) ? agg2[(size_t)gn * 256 + ko + kk] * 0.25f : 0.f;
    }
    __syncthreads();
    for (int kk = 0; kk < 64; ++kk) {
      const float a = tile[kk * 65 + l];
#pragma unroll
      for (int jj = 0; jj < 32; ++jj)
        acc[jj] = fmaf(a, w2[(ko + kk) * 128 + w * 32 + jj], acc[jj]);
    }
  }
  float po = 0.f;
  if (n < NN_) {
#pragma unroll
    for (int jj = 0; jj < 32; ++jj) {
      const int d = w * 32 + jj;
      const float v = acc[jj] + skipv[n * 128 + d];
      po = fmaf(silu_f(v), readout[d], po);
    }
  }
  partial[w * 64 + l] = po;
  __syncthreads();
  if (t < 64 && n0 + t < NN_) {
    out[n0 + t] = partial[t] + partial[64 + t] + partial[128 + t] + partial[192 + t];
  }
}

extern "C" void kernel_launch(void* const* d_in, const int* in_sizes, int n_in,
                              void* d_out, int out_size, void* d_ws, size_t ws_size,
                              hipStream_t stream) {
  const float* disp = (const float*)d_in[0];
  const int* species = (const int*)d_in[1];
  const int* senders = (const int*)d_in[2];
  const int* receivers = (const int*)d_in[3];
  const float* l1_lin1 = (const float*)d_in[4];
  const float* l1_rw0 = (const float*)d_in[5];
  const float* l1_rw1 = (const float*)d_in[6];
  const float* l1_rw2 = (const float*)d_in[7];
  const float* l1_rw3 = (const float*)d_in[8];
  const float* l1_w2s = (const float*)d_in[9];
  const float* l1_w2v = (const float*)d_in[10];
  const float* l1_skip = (const float*)d_in[11];
  const float* l2_lin1s = (const float*)d_in[12];
  const float* l2_lin1v = (const float*)d_in[13];
  const float* l2_rw0 = (const float*)d_in[14];
  const float* l2_rw1 = (const float*)d_in[15];
  const float* l2_rw2 = (const float*)d_in[16];
  const float* l2_rw3 = (const float*)d_in[17];
  const float* l2_w2 = (const float*)d_in[18];
  const float* l2_skip = (const float*)d_in[19];
  const float* readout_w = (const float*)d_in[20];

  // ---- workspace layout (elements), with lifetime overlays in `pool` ----
  float* ws = (float*)d_ws;
  float* rbc   = ws;               // E*8   [k1a -> k3a]
  float* y1    = ws + 2560000;     // E*4   [k1a -> k3b]
  float* s2    = ws + 3840000;     // N*128 [k2b -> k3b]
  float* v2    = ws + 6400000;     // N*384 [k2b -> k3b]
  float* skipv = ws + 14080000;    // N*128 [k2b -> k4]
  float* agg2  = ws + 16640000;    // N*256 [k3b -> k4]
  float* pool  = ws + 21760000;    // 20,480,000-float shared pool:
  float* agg_s = pool;             //   N*8        [k1b -> k2a]
  float* agg_v = pool + 160000;    //   N*24       [k1b -> k2a]
  float* buf1  = pool + 640000;    //   E*32       [k1a -> k1b]
  float* x0    = pool + 640000;    //   N*128      [k2a -> k2b] (over dead buf1)
  float* x1    = pool + 3200000;   //   N*384      [k2a -> k2b]
  float* r2    = pool;             //   EPH*256 = 20,480,000 exactly [k3a_q -> k3b_q]
  int* ibase   = (int*)(ws + 42240000);
  int* hist    = ibase;            // N
  int* cursor  = ibase + 20000;    // N
  int* offs    = ibase + 40000;    // N+1
  int* edge_id = ibase + 60001;    // E
  if (ws_size < (size_t)(42240000 + 380001) * 4) return;  // fail loudly, no scribble

  // ---- zero accumulators ----
  hipMemsetAsync(hist, 0, 20000 * sizeof(int), stream);
  hipMemsetAsync(agg2, 0, (size_t)5120000 * sizeof(float), stream);

  // ---- CSR build ----
  k_hist<<<EE_ / 256, 256, 0, stream>>>(receivers, hist);
  k_scan<<<1, 1024, 0, stream>>>(hist, offs, cursor);
  k_scatter<<<EE_ / 256, 256, 0, stream>>>(receivers, cursor, edge_id);

  // ---- layer 1 ----
  k1a_radial<<<EE_ / 128, 128, 0, stream>>>(disp, species, senders, l1_lin1,
                                            l1_rw0, l1_rw1, l1_rw2, l1_rw3,
                                            buf1, rbc, y1);
  k1b_gather<<<NN_ / 8, 256, 0, stream>>>(buf1, offs, edge_id, agg_s, agg_v);
  k2a_node<<<NN_, 64, 0, stream>>>(agg_s, agg_v, species, l1_w2s, l1_w2v, l1_skip,
                                   x0, x1);
  k2b_gemm<<<NN_ / 32, 256, 0, stream>>>(x0, x1, species, l2_lin1s, l2_lin1v,
                                         l2_skip, s2, v2, skipv);

  // ---- layer 2: 4 edge-phases (r2 buffer = one phase of R2 rows, CSR order) ----
  for (int q = 0; q < 4; ++q) {
    k3a_fused<<<EPH / 128, 128, 0, stream>>>(rbc, edge_id, l2_rw0, l2_rw1, l2_rw2,
                                             l2_rw3, r2, EPH * q);
    k3b_phase<<<NN_, 256, 0, stream>>>(r2, y1, senders, offs, edge_id, s2, v2,
                                       agg2, EPH * q, EPH * (q + 1));
  }
  k4_node<<<(NN_ + 63) / 64, 256, 0, stream>>>(agg2, skipv, l2_w2, readout_w,
                                               (float*)d_out);
}

// Round 13
// 1067.981 us; speedup vs baseline: 2.3572x; 2.3572x over previous
//
#include <hip/hip_runtime.h>
#include <math.h>

#define NN_ 20000
#define EE_ 320000
#define SHP 68      // padded row stride (floats) for [128][SHP] activation tile
#define EPH 80000   // edges per phase (E = 4 * EPH exactly)

__device__ __forceinline__ float silu_f(float x) { return x / (1.0f + expf(-x)); }

// ---- GEMM-tiled dense layer over a 128-edge LDS tile, 256 threads (4 waves) ----
// Wave w owns edges [w*32, w*32+32). Lane: eg = l>>3, jg = l&7.
// Thread tile: 4 edges (stride 8) x 8 outs. In-place + silu.
template<int KD>
__device__ __forceinline__ void layer_step(float* __restrict__ sh_h,
                                           const float* __restrict__ sh_w,
                                           int wavebase, int eg, int jg) {
  const int jb = jg * 8;
  float acc[4][8];
#pragma unroll
  for (int ee = 0; ee < 4; ++ee)
#pragma unroll
    for (int jj = 0; jj < 8; ++jj) acc[ee][jj] = 0.f;

#pragma unroll
  for (int kc = 0; kc < KD; kc += 4) {
    float4 w4[4][2];
#pragma unroll
    for (int kk = 0; kk < 4; ++kk) {
      w4[kk][0] = *(const float4*)&sh_w[(kc + kk) * 64 + jb];
      w4[kk][1] = *(const float4*)&sh_w[(kc + kk) * 64 + jb + 4];
    }
    float4 h4[4];
#pragma unroll
    for (int ee = 0; ee < 4; ++ee)
      h4[ee] = *(const float4*)&sh_h[(wavebase + eg + 8 * ee) * SHP + kc];
#pragma unroll
    for (int kk = 0; kk < 4; ++kk) {
#pragma unroll
      for (int ee = 0; ee < 4; ++ee) {
        const float hv = ((const float*)&h4[ee])[kk];
        acc[ee][0] = fmaf(hv, w4[kk][0].x, acc[ee][0]);
        acc[ee][1] = fmaf(hv, w4[kk][0].y, acc[ee][1]);
        acc[ee][2] = fmaf(hv, w4[kk][0].z, acc[ee][2]);
        acc[ee][3] = fmaf(hv, w4[kk][0].w, acc[ee][3]);
        acc[ee][4] = fmaf(hv, w4[kk][1].x, acc[ee][4]);
        acc[ee][5] = fmaf(hv, w4[kk][1].y, acc[ee][5]);
        acc[ee][6] = fmaf(hv, w4[kk][1].z, acc[ee][6]);
        acc[ee][7] = fmaf(hv, w4[kk][1].w, acc[ee][7]);
      }
    }
  }
#pragma unroll
  for (int ee = 0; ee < 4; ++ee) {
    float* dst = &sh_h[(wavebase + eg + 8 * ee) * SHP + jb];
    float4 lo = {silu_f(acc[ee][0]), silu_f(acc[ee][1]), silu_f(acc[ee][2]), silu_f(acc[ee][3])};
    float4 hi = {silu_f(acc[ee][4]), silu_f(acc[ee][5]), silu_f(acc[ee][6]), silu_f(acc[ee][7])};
    *(float4*)dst = lo;
    *(float4*)(dst + 4) = hi;
  }
}

// ---- same blocking, no activation, output -> global r2 rows -------------------
__device__ __forceinline__ void gemm_chunk_out(const float* __restrict__ sh_h,
                                               const float* __restrict__ sh_w,
                                               int wavebase, int eg, int jg,
                                               float* __restrict__ dst_base) {
  const int jb = jg * 8;
  float acc[4][8];
#pragma unroll
  for (int ee = 0; ee < 4; ++ee)
#pragma unroll
    for (int jj = 0; jj < 8; ++jj) acc[ee][jj] = 0.f;

#pragma unroll
  for (int kc = 0; kc < 64; kc += 4) {
    float4 w4[4][2];
#pragma unroll
    for (int kk = 0; kk < 4; ++kk) {
      w4[kk][0] = *(const float4*)&sh_w[(kc + kk) * 64 + jb];
      w4[kk][1] = *(const float4*)&sh_w[(kc + kk) * 64 + jb + 4];
    }
    float4 h4[4];
#pragma unroll
    for (int ee = 0; ee < 4; ++ee)
      h4[ee] = *(const float4*)&sh_h[(wavebase + eg + 8 * ee) * SHP + kc];
#pragma unroll
    for (int kk = 0; kk < 4; ++kk) {
#pragma unroll
      for (int ee = 0; ee < 4; ++ee) {
        const float hv = ((const float*)&h4[ee])[kk];
        acc[ee][0] = fmaf(hv, w4[kk][0].x, acc[ee][0]);
        acc[ee][1] = fmaf(hv, w4[kk][0].y, acc[ee][1]);
        acc[ee][2] = fmaf(hv, w4[kk][0].z, acc[ee][2]);
        acc[ee][3] = fmaf(hv, w4[kk][0].w, acc[ee][3]);
        acc[ee][4] = fmaf(hv, w4[kk][1].x, acc[ee][4]);
        acc[ee][5] = fmaf(hv, w4[kk][1].y, acc[ee][5]);
        acc[ee][6] = fmaf(hv, w4[kk][1].z, acc[ee][6]);
        acc[ee][7] = fmaf(hv, w4[kk][1].w, acc[ee][7]);
      }
    }
  }
#pragma unroll
  for (int ee = 0; ee < 4; ++ee) {
    float* dst = dst_base + (size_t)(wavebase + eg + 8 * ee) * 256 + jb;
    float4 lo = {acc[ee][0], acc[ee][1], acc[ee][2], acc[ee][3]};
    float4 hi = {acc[ee][4], acc[ee][5], acc[ee][6], acc[ee][7]};
    *(float4*)dst = lo;
    *(float4*)(dst + 4) = hi;
  }
}

__device__ __forceinline__ void load_w(const float* __restrict__ W, int nfloat,
                                       float* __restrict__ dst, int t) {
  for (int i = t * 4; i < nfloat; i += 1024) *(float4*)(dst + i) = *(const float4*)(W + i);
}

// ================= CSR construction (receiver-sorted edge ids) ====================
__global__ __launch_bounds__(256) void k_hist(const int* __restrict__ receivers,
                                              int* __restrict__ hist) {
  const int e = blockIdx.x * 256 + threadIdx.x;
  atomicAdd(&hist[receivers[e]], 1);
}

__global__ __launch_bounds__(1024) void k_scan(const int* __restrict__ hist,
                                               int* __restrict__ offs,
                                               int* __restrict__ cursor) {
  __shared__ int lds[1024];
  __shared__ int carry_s;
  const int t = threadIdx.x;
  if (t == 0) carry_s = 0;
  __syncthreads();
  for (int base = 0; base < NN_; base += 1024) {
    const int i = base + t;
    const int v = (i < NN_) ? hist[i] : 0;
    lds[t] = v;
    __syncthreads();
    for (int d = 1; d < 1024; d <<= 1) {
      const int tv = (t >= d) ? lds[t - d] : 0;
      __syncthreads();
      lds[t] += tv;
      __syncthreads();
    }
    const int inc = lds[t];
    const int c = carry_s;
    if (i < NN_) {
      const int off = c + inc - v;
      offs[i] = off;
      cursor[i] = off;
    }
    __syncthreads();
    if (t == 0) carry_s = c + lds[1023];
    __syncthreads();
  }
  if (t == 0) offs[NN_] = carry_s;
}

__global__ __launch_bounds__(256) void k_scatter(const int* __restrict__ receivers,
                                                 int* __restrict__ cursor,
                                                 int* __restrict__ edge_id) {
  const int e = blockIdx.x * 256 + threadIdx.x;
  const int r = receivers[e];
  const int pos = atomicAdd(&cursor[r], 1);
  edge_id[pos] = e;
}

// ---------------- K1a: per-edge layer-1 (geometry + tiled radial MLP + msg) -------
// 256 threads per 128-edge tile; geometry/head/messages on threads t<128.
__global__ __launch_bounds__(256, 3) void k1a_radial(
    const float* __restrict__ disp, const int* __restrict__ species,
    const int* __restrict__ senders,
    const float* __restrict__ lin1,
    const float* __restrict__ rw0, const float* __restrict__ rw1,
    const float* __restrict__ rw2, const float* __restrict__ rw3,
    float* __restrict__ buf1, float* __restrict__ rbc_g, float* __restrict__ y1_g) {
  __shared__ float sh_h[128 * SHP];
  __shared__ float sh_w[64 * 64];
  const int t = threadIdx.x;
  const int e0 = blockIdx.x * 128;
  const int e = e0 + (t & 127);

  float y1x = 0.f, y1y = 0.f, y1z = 0.f;
  if (t < 128) {
    const float dx = disp[e * 3 + 0], dy = disp[e * 3 + 1], dz = disp[e * 3 + 2];
    const float sq = dx * dx + dy * dy + dz * dz;
    const float rn = sqrtf(sq);
    const float inv = (rn == 0.f) ? 1.f : (1.f / rn);
    const float u = rn * 0.2f;
    float fc;
    {
      const float u2 = u * u;
      fc = 1.f - 6.f * u2 + 8.f * u2 * u - 3.f * u2 * u2;
      fc = (u < 1.f) ? fc : 0.f;
    }
    float rb[8];
#pragma unroll
    for (int k = 0; k < 8; ++k) {
      const float wk = (float)(k + 1) * 3.14159265358979323846f;
      const float s = (rn == 0.f) ? (wk * 0.2f) : (sinf(wk * u) * inv);
      rb[k] = 0.4f * s * fc;
    }
    float4 r0 = {rb[0], rb[1], rb[2], rb[3]};
    float4 r1 = {rb[4], rb[5], rb[6], rb[7]};
    *(float4*)(rbc_g + e * 8) = r0;
    *(float4*)(rbc_g + e * 8 + 4) = r1;
    y1x = 1.7320508075688772f * dx * inv;
    y1y = 1.7320508075688772f * dy * inv;
    y1z = 1.7320508075688772f * dz * inv;
    float4 y4 = {y1x, y1y, y1z, 0.f};
    *(float4*)(y1_g + e * 4) = y4;
    *(float4*)&sh_h[t * SHP] = r0;
    *(float4*)&sh_h[t * SHP + 4] = r1;
  }

  const int wavebase = (t >> 6) * 32;
  const int lane = t & 63;
  const int eg = lane >> 3, jg = lane & 7;

  load_w(rw0, 8 * 64, sh_w, t);
  __syncthreads();
  layer_step<8>(sh_h, sh_w, wavebase, eg, jg);
  __syncthreads();
  load_w(rw1, 64 * 64, sh_w, t);
  __syncthreads();
  layer_step<64>(sh_h, sh_w, wavebase, eg, jg);
  __syncthreads();
  load_w(rw2, 64 * 64, sh_w, t);
  __syncthreads();
  layer_step<64>(sh_h, sh_w, wavebase, eg, jg);
  __syncthreads();

  if (t < 128) {
    // ---- head 64->16 (thread t <-> edge t; rw3 via scalar loads) ----
    float R[16];
#pragma unroll
    for (int c = 0; c < 16; ++c) R[c] = 0.f;
    for (int k = 0; k < 64; ++k) {
      const float h = sh_h[t * SHP + k];
#pragma unroll
      for (int c = 0; c < 16; ++c) R[c] = fmaf(h, rw3[k * 16 + c], R[c]);
    }

    const int sp = species[senders[e]];
    float m[32];
#pragma unroll
    for (int c = 0; c < 8; ++c) {
      const float sc = lin1[sp * 8 + c];
      m[c] = sc * R[c];
      const float mv = sc * R[8 + c];
      m[8 + c * 3 + 0] = mv * y1x;
      m[8 + c * 3 + 1] = mv * y1y;
      m[8 + c * 3 + 2] = mv * y1z;
    }
    float* dst = buf1 + (size_t)e * 32;
#pragma unroll
    for (int q = 0; q < 8; ++q) {
      float4 v = {m[q * 4 + 0], m[q * 4 + 1], m[q * 4 + 2], m[q * 4 + 3]};
      *(float4*)(dst + q * 4) = v;
    }
  }
}

// ---------------- K3a: layer-2 radial MLP + 64->256 head GEMM (CSR order) ---------
// 256 threads per 128-CSR-position tile; writes R2 rows to r2buf[p - pbase].
__global__ __launch_bounds__(256, 3) void k3a_fused(
    const float* __restrict__ rbc_g, const int* __restrict__ edge_id,
    const float* __restrict__ rw0, const float* __restrict__ rw1,
    const float* __restrict__ rw2, const float* __restrict__ rw3,
    float* __restrict__ r2buf, int pbase) {
  __shared__ float sh_h[128 * SHP];
  __shared__ float sh_w[64 * 64];
  const int t = threadIdx.x;

  if (t < 128) {
    const int p = pbase + blockIdx.x * 128 + t;
    const int eid = edge_id[p];
    *(float4*)&sh_h[t * SHP] = *(const float4*)(rbc_g + (size_t)eid * 8);
    *(float4*)&sh_h[t * SHP + 4] = *(const float4*)(rbc_g + (size_t)eid * 8 + 4);
  }

  const int wavebase = (t >> 6) * 32;
  const int lane = t & 63;
  const int eg = lane >> 3, jg = lane & 7;

  load_w(rw0, 8 * 64, sh_w, t);
  __syncthreads();
  layer_step<8>(sh_h, sh_w, wavebase, eg, jg);
  __syncthreads();
  load_w(rw1, 64 * 64, sh_w, t);
  __syncthreads();
  layer_step<64>(sh_h, sh_w, wavebase, eg, jg);
  __syncthreads();
  load_w(rw2, 64 * 64, sh_w, t);
  __syncthreads();
  layer_step<64>(sh_h, sh_w, wavebase, eg, jg);

  // ---- R2 = h2(128x64) @ rw3(64x256), 4 column-chunks of 64 ----
  float* block_base = r2buf + (size_t)(blockIdx.x * 128) * 256;
  for (int c = 0; c < 4; ++c) {
    __syncthreads();  // prev chunk's sh_w reads (or layer3 sh_h writes) done
    // stage rw3[:, c*64 .. c*64+64) -> sh_w[k][j]
    for (int i = t * 4; i < 4096; i += 1024) {
      const int row = i >> 6, col = i & 63;
      *(float4*)&sh_w[i] = *(const float4*)&rw3[row * 256 + c * 64 + col];
    }
    __syncthreads();
    gemm_chunk_out(sh_h, sh_w, wavebase, eg, jg, block_base + c * 64);
  }
}

// ---------------- K3b: thin gather — agg2[n][ch] += sum tp * R2 -------------------
__global__ __launch_bounds__(256) void k3b_phase(
    const float* __restrict__ r2buf, const float* __restrict__ y1_g,
    const int* __restrict__ senders,
    const int* __restrict__ offs, const int* __restrict__ edge_id,
    const float* __restrict__ s2_g, const float* __restrict__ v2_g,
    float* __restrict__ agg2, int pbase, int pend) {
  const int n = blockIdx.x;
  const int ch = threadIdx.x;
  const int beg = offs[n], end = offs[n + 1];
  const int lo = beg > pbase ? beg : pbase;
  const int hi = end < pend ? end : pend;
  if (lo >= hi) return;
  const bool is_s = ch < 128;
  const int c3 = (ch - 128) * 3;
  float acc = 0.f;
  for (int i = lo; i < hi; ++i) {
    const int eid = __builtin_amdgcn_readfirstlane(edge_id[i]);
    const int s = __builtin_amdgcn_readfirstlane(senders[eid]);
    const float rv = r2buf[(size_t)(i - pbase) * 256 + ch];  // streaming, coalesced
    float tp;
    if (is_s) {
      tp = s2_g[(size_t)s * 128 + ch];
    } else {
      const float y1x = y1_g[eid * 4 + 0];
      const float y1y = y1_g[eid * 4 + 1];
      const float y1z = y1_g[eid * 4 + 2];
      tp = (v2_g[(size_t)s * 384 + c3 + 0] * y1x +
            v2_g[(size_t)s * 384 + c3 + 1] * y1y +
            v2_g[(size_t)s * 384 + c3 + 2] * y1z) * 0.5773502691896258f;
    }
    acc = fmaf(tp, rv, acc);
  }
  agg2[(size_t)n * 256 + ch] += acc;  // phases serialized on stream; agg2 pre-zeroed
}

// ---------------- K1b: per-node gather of layer-1 messages ------------------------
__global__ __launch_bounds__(256) void k1b_gather(
    const float* __restrict__ buf1, const int* __restrict__ offs,
    const int* __restrict__ edge_id,
    float* __restrict__ agg_s, float* __restrict__ agg_v) {
  const int n = blockIdx.x * 8 + (threadIdx.x >> 5);
  const int ch = threadIdx.x & 31;
  const int beg = offs[n], end = offs[n + 1];
  float acc = 0.f;
  for (int i = beg; i < end; ++i) {
    const int eid = edge_id[i];
    acc += buf1[(size_t)eid * 32 + ch];
  }
  if (ch < 8) agg_s[n * 8 + ch] = acc;
  else agg_v[n * 24 + (ch - 8)] = acc;
}

// ---------------- K2a: per-node layer-1 update (scal, x0, x1) ---------------------
__global__ __launch_bounds__(64) void k2a_node(
    const float* __restrict__ agg_s, const float* __restrict__ agg_v,
    const int* __restrict__ species,
    const float* __restrict__ w2s, const float* __restrict__ w2v,
    const float* __restrict__ skip1,
    float* __restrict__ x0_g, float* __restrict__ x1_g) {
  const int n = blockIdx.x;
  const int l = threadIdx.x;
  __shared__ float g_lds[128];
  const int sp = species[n];
  float as[8];
#pragma unroll
  for (int k = 0; k < 8; ++k) as[k] = agg_s[n * 8 + k] * 0.25f;
  float sc[4];
#pragma unroll
  for (int j = 0; j < 4; ++j) {
    const int d = l * 4 + j;
    float a = skip1[(sp * 9) * 256 + d];
#pragma unroll
    for (int k = 0; k < 8; ++k) a = fmaf(as[k], w2s[k * 256 + d], a);
    sc[j] = silu_f(a);
  }
  if (l < 32) {
#pragma unroll
    for (int j = 0; j < 4; ++j) x0_g[n * 128 + l * 4 + j] = sc[j];
  } else {
#pragma unroll
    for (int j = 0; j < 4; ++j) g_lds[(l - 32) * 4 + j] = sc[j];
  }
  __syncthreads();
  float av[24];
#pragma unroll
  for (int k = 0; k < 24; ++k) av[k] = agg_v[n * 24 + k] * 0.25f;
#pragma unroll
  for (int h = 0; h < 2; ++h) {
    const int d = l + h * 64;
    const float g = g_lds[d];
    float v0 = 0.f, v1 = 0.f, v2v = 0.f;
#pragma unroll
    for (int c = 0; c < 8; ++c) {
      const float w = w2v[c * 128 + d];
      v0 = fmaf(av[c * 3 + 0], w, v0);
      v1 = fmaf(av[c * 3 + 1], w, v1);
      v2v = fmaf(av[c * 3 + 2], w, v2v);
    }
    x1_g[(n * 3 + 0) * 128 + d] = v0 * g;
    x1_g[(n * 3 + 1) * 128 + d] = v1 * g;
    x1_g[(n * 3 + 2) * 128 + d] = v2v * g;
  }
}

// ---------------- K2b: node GEMMs (s2, v2, species-skip) --------------------------
__global__ __launch_bounds__(256) void k2b_gemm(
    const float* __restrict__ x0_g, const float* __restrict__ x1_g,
    const int* __restrict__ species,
    const float* __restrict__ lin1s, const float* __restrict__ lin1v,
    const float* __restrict__ skip2,
    float* __restrict__ s2_g, float* __restrict__ v2_g,
    float* __restrict__ skipv_g) {
  const int w = __builtin_amdgcn_readfirstlane((int)(threadIdx.x >> 6));
  const int l = threadIdx.x & 63;
  const int nbase = blockIdx.x * 32 + w * 8;
  float s2a[8] = {}, s2b[8] = {}, ska[8] = {}, skb[8] = {};
  float v2a[8][3] = {}, v2b[8][3] = {};
  int sp[8];
#pragma unroll
  for (int nn = 0; nn < 8; ++nn) sp[nn] = species[nbase + nn];
  for (int c = 0; c < 128; ++c) {
    const float wA0 = lin1s[c * 128 + l];
    const float wA1 = lin1s[c * 128 + 64 + l];
    const float wB0 = lin1v[c * 128 + l];
    const float wB1 = lin1v[c * 128 + 64 + l];
#pragma unroll
    for (int nn = 0; nn < 8; ++nn) {
      const int n = nbase + nn;
      const float x0v = x0_g[n * 128 + c];
      const float wS0 = skip2[sp[nn] * 16384 + c * 128 + l];
      const float wS1 = skip2[sp[nn] * 16384 + c * 128 + 64 + l];
      s2a[nn] = fmaf(x0v, wA0, s2a[nn]);
      s2b[nn] = fmaf(x0v, wA1, s2b[nn]);
      ska[nn] = fmaf(x0v, wS0, ska[nn]);
      skb[nn] = fmaf(x0v, wS1, skb[nn]);
#pragma unroll
      for (int i = 0; i < 3; ++i) {
        const float x1v = x1_g[(n * 3 + i) * 128 + c];
        v2a[nn][i] = fmaf(x1v, wB0, v2a[nn][i]);
        v2b[nn][i] = fmaf(x1v, wB1, v2b[nn][i]);
      }
    }
  }
#pragma unroll
  for (int nn = 0; nn < 8; ++nn) {
    const int n = nbase + nn;
    s2_g[n * 128 + l] = s2a[nn];
    s2_g[n * 128 + 64 + l] = s2b[nn];
    skipv_g[n * 128 + l] = ska[nn];
    skipv_g[n * 128 + 64 + l] = skb[nn];
#pragma unroll
    for (int i = 0; i < 3; ++i) {
      v2_g[n * 384 + l * 3 + i] = v2a[nn][i];
      v2_g[n * 384 + (64 + l) * 3 + i] = v2b[nn][i];
    }
  }
}

// ---------------- K4: final node update + readout ---------------------------------
__global__ __launch_bounds__(256) void k4_node(
    const float* __restrict__ agg2, const float* __restrict__ skipv,
    const float* __restrict__ w2, const float* __restrict__ readout,
    float* __restrict__ out) {
  __shared__ float tile[64 * 65];
  __shared__ float partial[256];
  const int t = threadIdx.x;
  const int w = __builtin_amdgcn_readfirstlane((int)(threadIdx.x >> 6));
  const int l = t & 63;
  const int n0 = blockIdx.x * 64;
  const int n = n0 + l;
  float acc[32];
#pragma unroll
  for (int j = 0; j < 32; ++j) acc[j] = 0.f;
  for (int ko = 0; ko < 256; ko += 64) {
    __syncthreads();
#pragma unroll
    for (int rep = 0; rep < 16; ++rep) {
      const int lin = rep * 256 + t;
      const int node = lin >> 6, kk = lin & 63;
      const int gn = n0 + node;
      tile[kk * 65 + node] = (gn < NN_) ? agg2[(size_t)gn * 256 + ko + kk] * 0.25f : 0.f;
    }
    __syncthreads();
    for (int kk = 0; kk < 64; ++kk) {
      const float a = tile[kk * 65 + l];
#pragma unroll
      for (int jj = 0; jj < 32; ++jj)
        acc[jj] = fmaf(a, w2[(ko + kk) * 128 + w * 32 + jj], acc[jj]);
    }
  }
  float po = 0.f;
  if (n < NN_) {
#pragma unroll
    for (int jj = 0; jj < 32; ++jj) {
      const int d = w * 32 + jj;
      const float v = acc[jj] + skipv[n * 128 + d];
      po = fmaf(silu_f(v), readout[d], po);
    }
  }
  partial[w * 64 + l] = po;
  __syncthreads();
  if (t < 64 && n0 + t < NN_) {
    out[n0 + t] = partial[t] + partial[64 + t] + partial[128 + t] + partial[192 + t];
  }
}

extern "C" void kernel_launch(void* const* d_in, const int* in_sizes, int n_in,
                              void* d_out, int out_size, void* d_ws, size_t ws_size,
                              hipStream_t stream) {
  const float* disp = (const float*)d_in[0];
  const int* species = (const int*)d_in[1];
  const int* senders = (const int*)d_in[2];
  const int* receivers = (const int*)d_in[3];
  const float* l1_lin1 = (const float*)d_in[4];
  const float* l1_rw0 = (const float*)d_in[5];
  const float* l1_rw1 = (const float*)d_in[6];
  const float* l1_rw2 = (const float*)d_in[7];
  const float* l1_rw3 = (const float*)d_in[8];
  const float* l1_w2s = (const float*)d_in[9];
  const float* l1_w2v = (const float*)d_in[10];
  const float* l1_skip = (const float*)d_in[11];
  const float* l2_lin1s = (const float*)d_in[12];
  const float* l2_lin1v = (const float*)d_in[13];
  const float* l2_rw0 = (const float*)d_in[14];
  const float* l2_rw1 = (const float*)d_in[15];
  const float* l2_rw2 = (const float*)d_in[16];
  const float* l2_rw3 = (const float*)d_in[17];
  const float* l2_w2 = (const float*)d_in[18];
  const float* l2_skip = (const float*)d_in[19];
  const float* readout_w = (const float*)d_in[20];

  // ---- workspace layout (elements), with lifetime overlays in `pool` ----
  float* ws = (float*)d_ws;
  float* rbc   = ws;               // E*8   [k1a -> k3a]
  float* y1    = ws + 2560000;     // E*4   [k1a -> k3b]
  float* s2    = ws + 3840000;     // N*128 [k2b -> k3b]
  float* v2    = ws + 6400000;     // N*384 [k2b -> k3b]
  float* skipv = ws + 14080000;    // N*128 [k2b -> k4]
  float* agg2  = ws + 16640000;    // N*256 [k3b -> k4]
  float* pool  = ws + 21760000;    // 20,480,000-float shared pool:
  float* agg_s = pool;             //   N*8        [k1b -> k2a]
  float* agg_v = pool + 160000;    //   N*24       [k1b -> k2a]
  float* buf1  = pool + 640000;    //   E*32       [k1a -> k1b]
  float* x0    = pool + 640000;    //   N*128      [k2a -> k2b] (over dead buf1)
  float* x1    = pool + 3200000;   //   N*384      [k2a -> k2b]
  float* r2    = pool;             //   EPH*256 = 20,480,000 exactly [k3a_q -> k3b_q]
  int* ibase   = (int*)(ws + 42240000);
  int* hist    = ibase;            // N
  int* cursor  = ibase + 20000;    // N
  int* offs    = ibase + 40000;    // N+1
  int* edge_id = ibase + 60001;    // E
  if (ws_size < (size_t)(42240000 + 380001) * 4) return;  // fail loudly, no scribble

  // ---- zero accumulators ----
  hipMemsetAsync(hist, 0, 20000 * sizeof(int), stream);
  hipMemsetAsync(agg2, 0, (size_t)5120000 * sizeof(float), stream);

  // ---- CSR build ----
  k_hist<<<EE_ / 256, 256, 0, stream>>>(receivers, hist);
  k_scan<<<1, 1024, 0, stream>>>(hist, offs, cursor);
  k_scatter<<<EE_ / 256, 256, 0, stream>>>(receivers, cursor, edge_id);

  // ---- layer 1 ----
  k1a_radial<<<EE_ / 128, 256, 0, stream>>>(disp, species, senders, l1_lin1,
                                            l1_rw0, l1_rw1, l1_rw2, l1_rw3,
                                            buf1, rbc, y1);
  k1b_gather<<<NN_ / 8, 256, 0, stream>>>(buf1, offs, edge_id, agg_s, agg_v);
  k2a_node<<<NN_, 64, 0, stream>>>(agg_s, agg_v, species, l1_w2s, l1_w2v, l1_skip,
                                   x0, x1);
  k2b_gemm<<<NN_ / 32, 256, 0, stream>>>(x0, x1, species, l2_lin1s, l2_lin1v,
                                         l2_skip, s2, v2, skipv);

  // ---- layer 2: 4 edge-phases (r2 buffer = one phase of R2 rows, CSR order) ----
  for (int q = 0; q < 4; ++q) {
    k3a_fused<<<EPH / 128, 256, 0, stream>>>(rbc, edge_id, l2_rw0, l2_rw1, l2_rw2,
                                             l2_rw3, r2, EPH * q);
    k3b_phase<<<NN_, 256, 0, stream>>>(r2, y1, senders, offs, edge_id, s2, v2,
                                       agg2, EPH * q, EPH * (q + 1));
  }
  k4_node<<<(NN_ + 63) / 64, 256, 0, stream>>>(agg2, skipv, l2_w2, readout_w,
                                               (float*)d_out);
}